// Round 3
// baseline (557.427 us; speedup 1.0000x reference)
//
#include <hip/hip_runtime.h>

#define NB   4
#define H_IN 14
#define W_IN 14
#define FIN  32
#define DI   8
#define F    32
#define C    288   // 3*3*32
#define DO   16
#define HO   12
#define WO   12
#define NPOS (NB*HO*WO)   // 576
#define EPS  1e-7f

#define G    8            // positions per block in kernels A/C
#define NPG  (NPOS/G)     // 72 position groups

#define AGR_BYTES   ((size_t)NPOS*F*C*4)      // 21,233,664
#define STATS_BYTES ((size_t)NPOS*C*8)        // 1,327,104

__device__ __forceinline__ float dot8f(const float4 w0, const float4 w1,
                                       const float4 p0, const float4 p1) {
    return w0.x*p0.x + w0.y*p0.y + w0.z*p0.z + w0.w*p0.w
         + w1.x*p1.x + w1.y*p1.y + w1.z*p1.z + w1.w*p1.w;
}

// Load patches for G=8 positions into LDS: 72 segments of 256 floats, float4-vectorized.
// Each 64-lane quarter of the block handles one segment per round (seg uniform per wave).
__device__ __forceinline__ void load_patches(const float* __restrict__ x,
                                             float (*patch)[C*DI],
                                             const int pg, const int tid) {
    const int lane = tid & 63;
    #pragma unroll 3
    for (int r = 0; r < 18; ++r) {
        const int seg  = r*4 + (tid >> 6);        // 0..71
        const int p    = seg / 9;
        const int slab = seg % 9;
        const int pos  = pg*G + p;
        const int b    = pos / (HO*WO);
        const int rem  = pos % (HO*WO);
        const int ho   = rem / WO;
        const int wo   = rem % WO;
        const int kh   = slab / 3, kw = slab % 3;
        const float4* src = (const float4*)(x + (((b*H_IN + ho + kh)*W_IN + (wo + kw))*FIN)*DI);
        ((float4*)&patch[p][slab*256])[lane] = src[lane];
    }
}

// ---- Kernel A: phases 2-4 for one filter f, G positions. Writes agr[pos][f][c]. ----
__global__ __launch_bounds__(256) void kernA(const float* __restrict__ x,
                                             const float* __restrict__ Wt,
                                             float* __restrict__ agr)
{
    __shared__ float patch[G][C*DI];   // 73728 B
    __shared__ float out1_s[G][DO];    // 512 B

    const int f   = blockIdx.x;
    const int pg  = blockIdx.y;
    const int tid = threadIdx.x;

    load_patches(x, patch, pg, tid);
    __syncthreads();

    // phase 2: cent1[p,o] = (1/32) * sum_{c,i} W[f,c,o,i]*patch[p,c,i]
    // thread -> p = tid>>5 (0..7), half = (tid>>4)&1, o = tid&15 (each half does 144 c's)
    {
        const int p = tid >> 5, half = (tid >> 4) & 1, o = tid & 15;
        const float* wbase = Wt + ((size_t)(f*C)*DO + o)*DI;
        float acc = 0.f;
        const int c0 = half*144;
        #pragma unroll 4
        for (int c = c0; c < c0 + 144; ++c) {
            const float4* wr = (const float4*)(wbase + (size_t)c*DO*DI);
            const float4* pp = (const float4*)&patch[p][c*DI];
            acc += dot8f(wr[0], wr[1], pp[0], pp[1]);
        }
        acc += __shfl_xor(acc, 16);         // combine c-halves
        const float cent1 = acc * (1.f/32.f);
        float sn = cent1*cent1;             // squash: reduce over o (lanes xor 1,2,4,8)
        sn += __shfl_xor(sn, 1);
        sn += __shfl_xor(sn, 2);
        sn += __shfl_xor(sn, 4);
        sn += __shfl_xor(sn, 8);
        const float sc = (sn/(1.f + sn)) * rsqrtf(sn + EPS);
        out1_s[p][o] = cent1 * sc;
    }
    __syncthreads();

    // phase 4: agr[p,c] = sum_o out1[p,o] * (sum_i W[f,c,o,i]*patch[p,c,i])
    {
        const int p = tid >> 5, cl = tid & 31;
        #pragma unroll 1
        for (int cc = 0; cc < C/32; ++cc) {   // 9 rounds
            const int c = cl + 32*cc;
            const float* wrow = Wt + (size_t)(f*C + c)*DO*DI;
            const float4* pp  = (const float4*)&patch[p][c*DI];
            const float4 pa = pp[0], pb = pp[1];
            float a = 0.f;
            #pragma unroll
            for (int o = 0; o < DO; ++o) {
                const float4* wr = (const float4*)(wrow + o*DI);
                a += dot8f(wr[0], wr[1], pa, pb) * out1_s[p][o];
            }
            agr[((size_t)(pg*G + p)*F + f)*C + c] = a;
        }
    }
}

// ---- Kernel B: softmax stats over f per (pos, c): max and 1/sum(exp). ----
__global__ __launch_bounds__(256) void kernB(const float* __restrict__ agr,
                                             float2* __restrict__ stats)
{
    __shared__ float s_agr[F*C];   // 36864 B
    const int pos = blockIdx.x, tid = threadIdx.x;
    const float4* src = (const float4*)(agr + (size_t)pos*F*C);
    float4* dst = (float4*)s_agr;
    #pragma unroll
    for (int r = 0; r < (F*C)/4/256; ++r)     // 9
        dst[r*256 + tid] = src[r*256 + tid];
    __syncthreads();
    for (int c = tid; c < C; c += 256) {
        float m = -1e30f;
        #pragma unroll
        for (int f = 0; f < F; ++f) m = fmaxf(m, s_agr[f*C + c]);
        float s = 0.f;
        #pragma unroll
        for (int f = 0; f < F; ++f) s += __expf(s_agr[f*C + c] - m);
        stats[(size_t)pos*C + c] = make_float2(m, 1.f/s);
    }
}

// ---- Kernel C: cc = softmax value, cent2 = sum_c cc*pred, squash, store. ----
__global__ __launch_bounds__(256) void kernC(const float* __restrict__ x,
                                             const float* __restrict__ Wt,
                                             const float* __restrict__ agr,
                                             const float2* __restrict__ stats,
                                             float* __restrict__ out)
{
    __shared__ float patch[G][C*DI];   // 73728 B
    __shared__ float cc_s[G][C];       // 9216 B

    const int f   = blockIdx.x;
    const int pg  = blockIdx.y;
    const int tid = threadIdx.x;

    load_patches(x, patch, pg, tid);

    // cc[p][c] = exp(agr - m) * inv_s   (2304 values, 9 per thread, coalesced)
    #pragma unroll 1
    for (int r = 0; r < (G*C)/256; ++r) {     // 9
        const int idx = r*256 + tid;
        const int p = idx / C, c = idx % C;
        const int pos = pg*G + p;
        const float  a  = agr[((size_t)pos*F + f)*C + c];
        const float2 st = stats[(size_t)pos*C + c];
        cc_s[p][c] = __expf(a - st.x) * st.y;
    }
    __syncthreads();

    // cent2[p,o] = sum_c cc[p,c] * (sum_i W[f,c,o,i]*patch[p,c,i])
    const int p = tid >> 5, half = (tid >> 4) & 1, o = tid & 15;
    const float* wbase = Wt + ((size_t)(f*C)*DO + o)*DI;
    float acc = 0.f;
    const int c0 = half*144;
    #pragma unroll 4
    for (int c = c0; c < c0 + 144; ++c) {
        const float4* wr = (const float4*)(wbase + (size_t)c*DO*DI);
        const float4* pp = (const float4*)&patch[p][c*DI];
        acc += cc_s[p][c] * dot8f(wr[0], wr[1], pp[0], pp[1]);
    }
    acc += __shfl_xor(acc, 16);               // combine c-halves
    float sn = acc*acc;                        // squash over o
    sn += __shfl_xor(sn, 1);
    sn += __shfl_xor(sn, 2);
    sn += __shfl_xor(sn, 4);
    sn += __shfl_xor(sn, 8);
    const float sc = (sn/(1.f + sn)) * rsqrtf(sn + EPS);
    if (half == 0)
        out[((size_t)(pg*G + p)*F + f)*DO + o] = acc * sc;
}

// -------- fp32 single-kernel fallback (if ws too small) ------------------------
__device__ __forceinline__ float dot8(const float4* __restrict__ w,
                                      const float4 p0, const float4 p1) {
    float4 a = w[0], b = w[1];
    return a.x*p0.x + a.y*p0.y + a.z*p0.z + a.w*p0.w
         + b.x*p1.x + b.y*p1.y + b.z*p1.z + b.w*p1.w;
}

__global__ __launch_bounds__(256) void capsule_kernel_f32(
    const float* __restrict__ x, const float* __restrict__ Wt,
    float* __restrict__ out)
{
    __shared__ float patch[C*DI];
    __shared__ float cent[F*DO];
    __shared__ float out1[F*DO];
    __shared__ float agr[F*C];
    __shared__ float scale_s[F];

    const int tid = threadIdx.x;
    const int pos = blockIdx.x;
    const int b   = pos / (HO*WO);
    const int rem = pos % (HO*WO);
    const int ho  = rem / WO;
    const int wo  = rem % WO;

    #pragma unroll
    for (int slab = 0; slab < 9; ++slab) {
        const int kh = slab / 3, kw = slab % 3;
        const float* src = x + (((b*H_IN + ho + kh)*W_IN + (wo + kw))*FIN)*DI;
        patch[slab*256 + tid] = src[tid];
    }
    __syncthreads();

    const float4* pv = (const float4*)patch;

    {
        const int fo0 = tid, fo1 = tid + 256;
        const int f0 = fo0 >> 4, o0 = fo0 & 15;
        const int f1 = fo1 >> 4, o1 = fo1 & 15;
        float acc0 = 0.f, acc1 = 0.f;
        for (int c = 0; c < C; ++c) {
            const float4 p0 = pv[c*2], p1 = pv[c*2+1];
            acc0 += dot8((const float4*)(Wt + ((f0*C + c)*DO + o0)*DI), p0, p1);
            acc1 += dot8((const float4*)(Wt + ((f1*C + c)*DO + o1)*DI), p0, p1);
        }
        cent[fo0] = acc0 * (1.f/32.f);
        cent[fo1] = acc1 * (1.f/32.f);
    }
    __syncthreads();

    if (tid < F) {
        float sn = 0.f;
        #pragma unroll
        for (int o = 0; o < DO; ++o) { float v = cent[tid*DO + o]; sn += v*v; }
        const float sc = (sn/(1.f + sn)) * rsqrtf(sn + EPS);
        #pragma unroll
        for (int o = 0; o < DO; ++o) out1[tid*DO + o] = cent[tid*DO + o] * sc;
    }
    __syncthreads();

    #pragma unroll 1
    for (int r = 0; r < (F*C)/256; ++r) {
        const int pp = tid + 256*r;
        const int f = pp / C, c = pp % C;
        const float4* wrow = (const float4*)(Wt + (f*C + c)*DO*DI);
        const float4 p0 = pv[c*2], p1 = pv[c*2+1];
        float a = 0.f;
        #pragma unroll
        for (int o = 0; o < DO; ++o) a += dot8(wrow + o*2, p0, p1) * out1[f*DO + o];
        agr[pp] = a;
    }
    __syncthreads();

    for (int c = tid; c < C; c += 256) {
        float m = -1e30f;
        #pragma unroll
        for (int f = 0; f < F; ++f) m = fmaxf(m, agr[f*C + c]);
        float s = 0.f;
        #pragma unroll
        for (int f = 0; f < F; ++f) {
            const float e = __expf(agr[f*C + c] - m);
            agr[f*C + c] = e; s += e;
        }
        const float inv = 1.f / s;
        #pragma unroll
        for (int f = 0; f < F; ++f) agr[f*C + c] *= inv;
    }
    __syncthreads();

    {
        const int fo0 = tid, fo1 = tid + 256;
        const int f0 = fo0 >> 4, o0 = fo0 & 15;
        const int f1 = fo1 >> 4, o1 = fo1 & 15;
        float acc0 = 0.f, acc1 = 0.f;
        for (int c = 0; c < C; ++c) {
            const float4 p0 = pv[c*2], p1 = pv[c*2+1];
            acc0 += agr[f0*C + c] * dot8((const float4*)(Wt + ((f0*C + c)*DO + o0)*DI), p0, p1);
            acc1 += agr[f1*C + c] * dot8((const float4*)(Wt + ((f1*C + c)*DO + o1)*DI), p0, p1);
        }
        cent[fo0] = acc0;
        cent[fo1] = acc1;
    }
    __syncthreads();

    if (tid < F) {
        float sn = 0.f;
        #pragma unroll
        for (int o = 0; o < DO; ++o) { float v = cent[tid*DO + o]; sn += v*v; }
        scale_s[tid] = (sn/(1.f + sn)) * rsqrtf(sn + EPS);
    }
    __syncthreads();

    out[pos*(F*DO) + tid]       = cent[tid]       * scale_s[tid >> 4];
    out[pos*(F*DO) + tid + 256] = cent[tid + 256] * scale_s[(tid >> 4) + 16];
}

extern "C" void kernel_launch(void* const* d_in, const int* in_sizes, int n_in,
                              void* d_out, int out_size, void* d_ws, size_t ws_size,
                              hipStream_t stream) {
    const float* x  = (const float*)d_in[0];
    const float* Wt = (const float*)d_in[1];
    float* out = (float*)d_out;

    if (ws_size >= AGR_BYTES + STATS_BYTES) {
        float*  agr   = (float*)d_ws;
        float2* stats = (float2*)((char*)d_ws + AGR_BYTES);
        kernA<<<dim3(F, NPG), 256, 0, stream>>>(x, Wt, agr);
        kernB<<<NPOS, 256, 0, stream>>>(agr, stats);
        kernC<<<dim3(F, NPG), 256, 0, stream>>>(x, Wt, agr, stats, out);
    } else {
        capsule_kernel_f32<<<NPOS, 256, 0, stream>>>(x, Wt, out);
    }
}

// Round 4
// 373.082 us; speedup vs baseline: 1.4941x; 1.4941x over previous
//
#include <hip/hip_runtime.h>

#define NB   4
#define H_IN 14
#define W_IN 14
#define FIN  32
#define DI   8
#define F    32
#define C    288   // 3*3*32
#define DO   16
#define HO   12
#define WO   12
#define NPOS (NB*HO*WO)   // 576
#define EPS  1e-7f

#define CH1  4             // c-chunks in kern1
#define CC1  (C/CH1)       // 72
#define CH2  8             // c-chunks in kern2
#define CC2  (C/CH2)       // 36
#define GP   8             // positions per block
#define NPG  (NPOS/GP)     // 72

#define W2_BYTES  ((size_t)F*C*DO*DI*4)        // 4,718,592
#define WS1_BYTES ((size_t)CH1*NPOS*F*DO*4)    // 4,718,592
#define WS2_BYTES ((size_t)CH2*NPOS*F*DO*4)    // 9,437,184

// ---- transpose W[f][c][o][i] -> W2[c][o][f][i] (coalesced writes) -------------
__global__ __launch_bounds__(256) void kernT(const float* __restrict__ Wt,
                                             float* __restrict__ W2) {
    const int idx4 = blockIdx.x*256 + threadIdx.x;   // output float4 index
    const int i2 = idx4 & 1;
    const int f  = (idx4 >> 1) & 31;
    const int o  = (idx4 >> 6) & 15;
    const int c  = idx4 >> 10;
    ((float4*)W2)[idx4] = ((const float4*)Wt)[((size_t)(f*C + c)*DO + o)*2 + i2];
}

// ---- kern1: cent1 partials over a c-chunk. thread=(f,p), all-register. --------
__global__ __launch_bounds__(256) void kern1(const float* __restrict__ x,
                                             const float* __restrict__ W2,
                                             float* __restrict__ ws1)
{
    const int tid = threadIdx.x;
    const int f = tid & 31, p = tid >> 5;
    const int ch = blockIdx.x, pg = blockIdx.y;
    const int pos = pg*GP + p;
    const int b = pos/(HO*WO), rem = pos%(HO*WO), ho = rem/WO, wo = rem%WO;

    const float4* W2f4 = (const float4*)W2;
    float acc[DO];
    #pragma unroll
    for (int o = 0; o < DO; ++o) acc[o] = 0.f;

    const int c0 = ch*CC1;
    #pragma unroll 2
    for (int c = c0; c < c0 + CC1; ++c) {
        const int slab = c >> 5, fin = c & 31;
        const int kh = slab/3, kw = slab%3;
        const float4* px = (const float4*)(x + (size_t)(((b*H_IN + ho+kh)*W_IN + wo+kw)*FIN + fin)*DI);
        const float4 p0 = px[0], p1 = px[1];
        const float4* wb = W2f4 + (size_t)c*(DO*F*2) + f*2;
        #pragma unroll
        for (int o = 0; o < DO; ++o) {
            const float4 w0 = wb[o*64], w1 = wb[o*64 + 1];
            acc[o] += w0.x*p0.x + w0.y*p0.y + w0.z*p0.z + w0.w*p0.w
                    + w1.x*p1.x + w1.y*p1.y + w1.z*p1.z + w1.w*p1.w;
        }
    }
    float4* dst = (float4*)(ws1 + ((size_t)(ch*NPOS + pos)*F + f)*DO);
    dst[0] = make_float4(acc[0], acc[1], acc[2], acc[3]);
    dst[1] = make_float4(acc[4], acc[5], acc[6], acc[7]);
    dst[2] = make_float4(acc[8], acc[9], acc[10], acc[11]);
    dst[3] = make_float4(acc[12], acc[13], acc[14], acc[15]);
}

// ---- kern2: out1 from cent1; per-c pred/agr/softmax_f/cent2-accumulate. -------
__global__ __launch_bounds__(256) void kern2(const float* __restrict__ x,
                                             const float* __restrict__ W2,
                                             const float* __restrict__ ws1,
                                             float* __restrict__ ws2)
{
    const int tid = threadIdx.x;
    const int f = tid & 31, p = tid >> 5;
    const int ch = blockIdx.x, pg = blockIdx.y;
    const int pos = pg*GP + p;
    const int b = pos/(HO*WO), rem = pos%(HO*WO), ho = rem/WO, wo = rem%WO;

    // reduce cent1 partials, squash -> out1 (all in-thread)
    float cent1[DO];
    #pragma unroll
    for (int o = 0; o < DO; ++o) cent1[o] = 0.f;
    #pragma unroll
    for (int k = 0; k < CH1; ++k) {
        const float4* s = (const float4*)(ws1 + ((size_t)(k*NPOS + pos)*F + f)*DO);
        #pragma unroll
        for (int q = 0; q < 4; ++q) {
            const float4 v = s[q];
            cent1[q*4+0] += v.x; cent1[q*4+1] += v.y;
            cent1[q*4+2] += v.z; cent1[q*4+3] += v.w;
        }
    }
    float sn = 0.f;
    #pragma unroll
    for (int o = 0; o < DO; ++o) { cent1[o] *= (1.f/32.f); sn += cent1[o]*cent1[o]; }
    const float sc1 = (sn/(1.f + sn)) * rsqrtf(sn + EPS);
    float out1[DO];
    #pragma unroll
    for (int o = 0; o < DO; ++o) out1[o] = cent1[o]*sc1;

    const float4* W2f4 = (const float4*)W2;
    float cent2[DO];
    #pragma unroll
    for (int o = 0; o < DO; ++o) cent2[o] = 0.f;

    const int c0 = ch*CC2;
    #pragma unroll 1
    for (int c = c0; c < c0 + CC2; ++c) {
        const int slab = c >> 5, fin = c & 31;
        const int kh = slab/3, kw = slab%3;
        const float4* px = (const float4*)(x + (size_t)(((b*H_IN + ho+kh)*W_IN + wo+kw)*FIN + fin)*DI);
        const float4 p0 = px[0], p1 = px[1];
        const float4* wb = W2f4 + (size_t)c*(DO*F*2) + f*2;
        float pred[DO];
        #pragma unroll
        for (int o = 0; o < DO; ++o) {
            const float4 w0 = wb[o*64], w1 = wb[o*64 + 1];
            pred[o] = w0.x*p0.x + w0.y*p0.y + w0.z*p0.z + w0.w*p0.w
                    + w1.x*p1.x + w1.y*p1.y + w1.z*p1.z + w1.w*p1.w;
        }
        float agr = 0.f;
        #pragma unroll
        for (int o = 0; o < DO; ++o) agr += pred[o]*out1[o];
        // softmax over the 32 f-lanes (masks stay within the 32-lane f group)
        float m = agr;
        m = fmaxf(m, __shfl_xor(m, 1));
        m = fmaxf(m, __shfl_xor(m, 2));
        m = fmaxf(m, __shfl_xor(m, 4));
        m = fmaxf(m, __shfl_xor(m, 8));
        m = fmaxf(m, __shfl_xor(m, 16));
        const float e = __expf(agr - m);
        float s = e;
        s += __shfl_xor(s, 1);
        s += __shfl_xor(s, 2);
        s += __shfl_xor(s, 4);
        s += __shfl_xor(s, 8);
        s += __shfl_xor(s, 16);
        const float cc = e / s;
        #pragma unroll
        for (int o = 0; o < DO; ++o) cent2[o] += cc*pred[o];
    }
    float4* dst = (float4*)(ws2 + ((size_t)(ch*NPOS + pos)*F + f)*DO);
    dst[0] = make_float4(cent2[0], cent2[1], cent2[2], cent2[3]);
    dst[1] = make_float4(cent2[4], cent2[5], cent2[6], cent2[7]);
    dst[2] = make_float4(cent2[8], cent2[9], cent2[10], cent2[11]);
    dst[3] = make_float4(cent2[12], cent2[13], cent2[14], cent2[15]);
}

// ---- kern3: reduce cent2 chunks, squash, store. -------------------------------
__global__ __launch_bounds__(256) void kern3(const float* __restrict__ ws2,
                                             float* __restrict__ out)
{
    const int tid = threadIdx.x;
    const int f = tid & 31, p = tid >> 5;
    const int pos = blockIdx.x*GP + p;

    float cent[DO];
    #pragma unroll
    for (int o = 0; o < DO; ++o) cent[o] = 0.f;
    #pragma unroll
    for (int k = 0; k < CH2; ++k) {
        const float4* s = (const float4*)(ws2 + ((size_t)(k*NPOS + pos)*F + f)*DO);
        #pragma unroll
        for (int q = 0; q < 4; ++q) {
            const float4 v = s[q];
            cent[q*4+0] += v.x; cent[q*4+1] += v.y;
            cent[q*4+2] += v.z; cent[q*4+3] += v.w;
        }
    }
    float sn = 0.f;
    #pragma unroll
    for (int o = 0; o < DO; ++o) sn += cent[o]*cent[o];
    const float sc = (sn/(1.f + sn)) * rsqrtf(sn + EPS);
    float4* dst = (float4*)(out + ((size_t)pos*F + f)*DO);
    dst[0] = make_float4(cent[0]*sc,  cent[1]*sc,  cent[2]*sc,  cent[3]*sc);
    dst[1] = make_float4(cent[4]*sc,  cent[5]*sc,  cent[6]*sc,  cent[7]*sc);
    dst[2] = make_float4(cent[8]*sc,  cent[9]*sc,  cent[10]*sc, cent[11]*sc);
    dst[3] = make_float4(cent[12]*sc, cent[13]*sc, cent[14]*sc, cent[15]*sc);
}

// -------- fp32 single-kernel fallback (if ws too small) ------------------------
__device__ __forceinline__ float dot8(const float4* __restrict__ w,
                                      const float4 p0, const float4 p1) {
    float4 a = w[0], b = w[1];
    return a.x*p0.x + a.y*p0.y + a.z*p0.z + a.w*p0.w
         + b.x*p1.x + b.y*p1.y + b.z*p1.z + b.w*p1.w;
}

__global__ __launch_bounds__(256) void capsule_kernel_f32(
    const float* __restrict__ x, const float* __restrict__ Wt,
    float* __restrict__ out)
{
    __shared__ float patch[C*DI];
    __shared__ float cent[F*DO];
    __shared__ float out1[F*DO];
    __shared__ float agr[F*C];
    __shared__ float scale_s[F];

    const int tid = threadIdx.x;
    const int pos = blockIdx.x;
    const int b   = pos / (HO*WO);
    const int rem = pos % (HO*WO);
    const int ho  = rem / WO;
    const int wo  = rem % WO;

    #pragma unroll
    for (int slab = 0; slab < 9; ++slab) {
        const int kh = slab / 3, kw = slab % 3;
        const float* src = x + (((b*H_IN + ho + kh)*W_IN + (wo + kw))*FIN)*DI;
        patch[slab*256 + tid] = src[tid];
    }
    __syncthreads();

    const float4* pv = (const float4*)patch;

    {
        const int fo0 = tid, fo1 = tid + 256;
        const int f0 = fo0 >> 4, o0 = fo0 & 15;
        const int f1 = fo1 >> 4, o1 = fo1 & 15;
        float acc0 = 0.f, acc1 = 0.f;
        for (int c = 0; c < C; ++c) {
            const float4 p0 = pv[c*2], p1 = pv[c*2+1];
            acc0 += dot8((const float4*)(Wt + ((f0*C + c)*DO + o0)*DI), p0, p1);
            acc1 += dot8((const float4*)(Wt + ((f1*C + c)*DO + o1)*DI), p0, p1);
        }
        cent[fo0] = acc0 * (1.f/32.f);
        cent[fo1] = acc1 * (1.f/32.f);
    }
    __syncthreads();

    if (tid < F) {
        float sn = 0.f;
        #pragma unroll
        for (int o = 0; o < DO; ++o) { float v = cent[tid*DO + o]; sn += v*v; }
        const float sc = (sn/(1.f + sn)) * rsqrtf(sn + EPS);
        #pragma unroll
        for (int o = 0; o < DO; ++o) out1[tid*DO + o] = cent[tid*DO + o] * sc;
    }
    __syncthreads();

    #pragma unroll 1
    for (int r = 0; r < (F*C)/256; ++r) {
        const int pp = tid + 256*r;
        const int f = pp / C, c = pp % C;
        const float4* wrow = (const float4*)(Wt + (f*C + c)*DO*DI);
        const float4 p0 = pv[c*2], p1 = pv[c*2+1];
        float a = 0.f;
        #pragma unroll
        for (int o = 0; o < DO; ++o) a += dot8(wrow + o*2, p0, p1) * out1[f*DO + o];
        agr[pp] = a;
    }
    __syncthreads();

    for (int c = tid; c < C; c += 256) {
        float m = -1e30f;
        #pragma unroll
        for (int f = 0; f < F; ++f) m = fmaxf(m, agr[f*C + c]);
        float s = 0.f;
        #pragma unroll
        for (int f = 0; f < F; ++f) {
            const float e = __expf(agr[f*C + c] - m);
            agr[f*C + c] = e; s += e;
        }
        const float inv = 1.f / s;
        #pragma unroll
        for (int f = 0; f < F; ++f) agr[f*C + c] *= inv;
    }
    __syncthreads();

    {
        const int fo0 = tid, fo1 = tid + 256;
        const int f0 = fo0 >> 4, o0 = fo0 & 15;
        const int f1 = fo1 >> 4, o1 = fo1 & 15;
        float acc0 = 0.f, acc1 = 0.f;
        for (int c = 0; c < C; ++c) {
            const float4 p0 = pv[c*2], p1 = pv[c*2+1];
            acc0 += agr[f0*C + c] * dot8((const float4*)(Wt + ((f0*C + c)*DO + o0)*DI), p0, p1);
            acc1 += agr[f1*C + c] * dot8((const float4*)(Wt + ((f1*C + c)*DO + o1)*DI), p0, p1);
        }
        cent[fo0] = acc0;
        cent[fo1] = acc1;
    }
    __syncthreads();

    if (tid < F) {
        float sn = 0.f;
        #pragma unroll
        for (int o = 0; o < DO; ++o) { float v = cent[tid*DO + o]; sn += v*v; }
        scale_s[tid] = (sn/(1.f + sn)) * rsqrtf(sn + EPS);
    }
    __syncthreads();

    out[pos*(F*DO) + tid]       = cent[tid]       * scale_s[tid >> 4];
    out[pos*(F*DO) + tid + 256] = cent[tid + 256] * scale_s[(tid >> 4) + 16];
}

extern "C" void kernel_launch(void* const* d_in, const int* in_sizes, int n_in,
                              void* d_out, int out_size, void* d_ws, size_t ws_size,
                              hipStream_t stream) {
    const float* x  = (const float*)d_in[0];
    const float* Wt = (const float*)d_in[1];
    float* out = (float*)d_out;

    if (ws_size >= W2_BYTES + WS1_BYTES + WS2_BYTES) {
        float* W2  = (float*)d_ws;
        float* ws1 = (float*)((char*)d_ws + W2_BYTES);
        float* ws2 = (float*)((char*)d_ws + W2_BYTES + WS1_BYTES);
        kernT<<<(F*C*DO*DI)/4/256, 256, 0, stream>>>(Wt, W2);     // 1152 blocks
        kern1<<<dim3(CH1, NPG), 256, 0, stream>>>(x, W2, ws1);    // 288 blocks
        kern2<<<dim3(CH2, NPG), 256, 0, stream>>>(x, W2, ws1, ws2); // 576 blocks
        kern3<<<NPG, 256, 0, stream>>>(ws2, out);                 // 72 blocks
    } else {
        capsule_kernel_f32<<<NPOS, 256, 0, stream>>>(x, Wt, out);
    }
}